// Round 8
// baseline (144.128 us; speedup 1.0000x reference)
//
#include <hip/hip_runtime.h>
#include <stdint.h>

#define TT 25
#define SS 512
#define BB 4096
#define RST 36
#define IL2 1.4426950408889634f
#define LN2F 0.6931471805599453f

__device__ __forceinline__ float ex2(float x){ return __builtin_amdgcn_exp2f(x); }
__device__ __forceinline__ float lg2(float x){ return __builtin_amdgcn_logf(x); }
__device__ __forceinline__ int iclampi(int x,int lo,int hi){ return min(max(x,lo),hi); }

// pin a value into a VGPR: opaque def, LICM can't sink/remat the producer
#define PIN(x) asm volatile("" : "+v"(x))

// row_ror:K within each 16-lane row (VALU pipe, no LDS): dst[i] = src[(i-K)&15]
template<int K>
__device__ __forceinline__ float rotk(float v){
  if constexpr (K == 0) return v;
  else return __int_as_float(__builtin_amdgcn_update_dpp(
      0, __float_as_int(v), 0x120 | K, 0xF, 0xF, true));
}

#define SWZMAX(v,P) v = fmaxf(v, __int_as_float(__builtin_amdgcn_ds_swizzle(__float_as_int(v), P)))
#define SWZADD(v,P) v += __int_as_float(__builtin_amdgcn_ds_swizzle(__float_as_int(v), P))

// mask may arrive as bool(u8), int32, or float32 — detect from first element
__device__ __forceinline__ int mask_at(const void* m, int mode, int idx){
  if (mode == 1) return ((const int*)m)[idx] != 0;
  if (mode == 2) return ((const float*)m)[idx] != 0.0f;
  return ((const unsigned char*)m)[idx] != 0;
}

__global__ __attribute__((amdgpu_flat_work_group_size(256, 256),
                          amdgpu_waves_per_eu(2, 2)))
void crf_main(const float* __restrict__ em, const float* __restrict__ startp,
              const float* __restrict__ endp, const float* __restrict__ transp,
              const int* __restrict__ labels, const void* __restrict__ maskp,
              float* __restrict__ wsr, float* __restrict__ wsl)
{
  __shared__ float smem[16 * RST];   // epilogue only
  const int tid  = threadIdx.x;
  const int w    = tid >> 6;
  const int lane = tid & 63;
  const int g    = lane >> 4;        // chain-group 0..3 within wave
  const int lidx = lane & 15;
  const int dir  = g & 1;            // 0 = forward, 1 = backward
  const int rsel = g >> 1;           // which of the wave's 2 rows
  const int row  = blockIdx.x * 8 + w * 2 + rsel;
  const int rbS  = row * SS;
  const int rowbase = (w * 4 + g) * RST;

  const int c1 = 2 * lidx, c2 = 2 * lidx + 1;      // adjacent col pair
  const bool v1 = (c1 < TT), v2 = (c2 < TT);
  const int c1c = v1 ? c1 : (TT - 1), c2c = v2 ? c2 : (TT - 1);
  const int ws2 = (lidx <= 12) ? 2 * lidx : (26 + 2 * (lidx - 13)); // idle dump 26..31

  // --- mask dtype detection ---
  const uint32_t w0 = ((const uint32_t*)maskp)[0];
  const int mode = (w0 == 1u) ? 1 : ((w0 == 0x3F800000u) ? 2 : 0);

  // --- lengths of the wave's two rows (2-round ballot probes) ---
  int lens[2];
  const int base2row = blockIdx.x * 8 + w * 2;
#pragma unroll
  for (int r = 0; r < 2; ++r) {
    int mb = (base2row + r) * SS;
    int pq1 = mask_at(maskp, mode, mb + lane * 8);
    unsigned long long b1 = __ballot(pq1);
    int q = __popcll(b1);
    int bs = 8 * (q - 1);
    int pq2 = mask_at(maskp, mode, mb + bs + (lane & 7));
    unsigned long long b2 = __ballot((lane < 8) && pq2);
    lens[r] = bs + __popcll(b2);
  }
  const int L = rsel ? lens[1] : lens[0];
  const int m = (L - 1) >> 1;
  const int iters = dir ? (L - 1 - m) : m;
  const int it0 = lens[0] - 1 - ((lens[0] - 1) >> 1);
  const int it1 = lens[1] - 1 - ((lens[1] - 1) >> 1);
  const int maxIters = max(it0, it1);   // bwd count >= fwd count

  // --- pre-rotated weight tables. row_ror:k delivers src lane s=(lidx-k)&15,
  //     which holds cols i1=2s, i2=2s+1.  Ea1[k]: p_{i1} -> acc col c1, etc.
  //     fwd: E[i][c] = exp(trans[i][c]); bwd: exp(trans[c][i]).
  //     Zero where source col or own col invalid (keeps dead lanes exactly 0).
  float Ea1[16], Eb1[16], Ea2[16], Eb2[16];
#pragma unroll
  for (int k = 0; k < 16; ++k) {
    int s  = (lidx - k) & 15;          // ror:k source lane is lidx-k
    int i1 = 2 * s, i2 = 2 * s + 1;
    bool q1 = (i1 < TT), q2 = (i2 < TT);
    int i1c = q1 ? i1 : 0, i2c = q2 ? i2 : 0;
    float t11 = dir ? transp[c1c * TT + i1c] : transp[i1c * TT + c1c];
    float t21 = dir ? transp[c1c * TT + i2c] : transp[i2c * TT + c1c];
    float t12 = dir ? transp[c2c * TT + i1c] : transp[i1c * TT + c2c];
    float t22 = dir ? transp[c2c * TT + i2c] : transp[i2c * TT + c2c];
    Ea1[k] = (q1 && v1) ? ex2(t11 * IL2) : 0.f;
    Eb1[k] = (q2 && v1) ? ex2(t21 * IL2) : 0.f;
    Ea2[k] = (q1 && v2) ? ex2(t12 * IL2) : 0.f;
    Eb2[k] = (q2 && v2) ? ex2(t22 * IL2) : 0.f;
  }
  // pin all 64 table entries into VGPRs — without this, pressure-aware LICM
  // leaves the transp loads + v_exp_f32 INSIDE the step loop (R6: 265 instr/step)
#pragma unroll
  for (int k = 0; k < 16; ++k) {
    PIN(Ea1[k]); PIN(Eb1[k]); PIN(Ea2[k]); PIN(Eb2[k]);
  }

  // --- init state: fwd alpha0 = exp(start+em0); bwd gamma_{L-1} = exp(end) ---
  float pf1 = startp[c1c] + em[(size_t)rbS * TT + c1c];
  float pf2 = startp[c2c] + em[(size_t)rbS * TT + c2c];
  float p1 = v1 ? ex2((dir ? endp[c1c] : pf1) * IL2) : 0.f;
  float p2 = v2 ? ex2((dir ? endp[c2c] : pf2) * IL2) : 0.f;

  // --- numerator init + label carry ---
  const int l0 = labels[rbS];
  const int lE = labels[rbS + L - 1];
  float num = dir ? endp[lE] : (startp[l0] + em[(size_t)rbS * TT + l0]);
  int C2 = 0;
  int carry = dir ? lE : l0;

  // --- prefetch rings (depth 8; labels 16 ahead for the dependent trans gather) ---
  float emv1[8], emv2[8], tadd[8];
  int labv[8];
#pragma unroll
  for (int u = 0; u < 8; ++u) {
    int t = dir ? (L - 1 - u) : (1 + u);
    t = iclampi(t, 1, L - 1);
    size_t eb = (size_t)(rbS + t) * TT;
    emv1[u] = em[eb + c1c];
    emv2[u] = em[eb + c2c];
    int ni = dir ? (L - 2 - u) : (1 + u);
    ni = iclampi(ni, 0, L - 1);
    int nl = labels[rbS + ni];
    int aL = dir ? nl : carry, bL = dir ? carry : nl;
    tadd[u] = transp[aL * TT + bL] + em[eb + bL];
    carry = nl;
  }
#pragma unroll
  for (int u = 0; u < 8; ++u) {
    int ni = dir ? (L - 2 - (u + 8)) : (1 + u + 8);
    ni = iclampi(ni, 0, L - 1);
    labv[u] = labels[rbS + ni];
  }

  int ubase = 0;

#define ROTK(K)                                                               \
    { float r1 = rotk<K>(w1), r2 = rotk<K>(w2v);                              \
      d1a = fmaf(r1, Ea1[K], d1a); d1b = fmaf(r2, Eb1[K], d1b);               \
      d2a = fmaf(r1, Ea2[K], d2a); d2b = fmaf(r2, Eb2[K], d2b); }

#define STEP(u, FILL)                                                         \
  {                                                                           \
    const int uu = ubase + (u);                                               \
    float e1 = ex2(emv1[u] * IL2), e2 = ex2(emv2[u] * IL2);                   \
    float ta = tadd[u];                                                       \
    bool live = uu < iters;                                                   \
    num += live ? ta : 0.f;                                                   \
    if (FILL) {                                                               \
      int vf = uu + 8;                                                        \
      int t = dir ? (L - 1 - vf) : (1 + vf);                                  \
      t = iclampi(t, 1, L - 1);                                               \
      size_t eb = (size_t)(rbS + t) * TT;                                     \
      emv1[u] = em[eb + c1c];                                                 \
      emv2[u] = em[eb + c2c];                                                 \
      int nl = labv[u];                                                       \
      int aL = dir ? nl : carry, bL = dir ? carry : nl;                       \
      tadd[u] = transp[aL * TT + bL] + em[eb + bL];                           \
      int ni = dir ? (L - 2 - (vf + 8)) : (1 + vf + 8);                       \
      ni = iclampi(ni, 0, L - 1);                                             \
      labv[u] = labels[rbS + ni];                                             \
      carry = nl;                                                             \
    }                                                                         \
    float w1 = dir ? p1 * e1 : p1, w2v = dir ? p2 * e2 : p2;                  \
    float d1a = 0.f, d1b = 0.f, d2a = 0.f, d2b = 0.f;                         \
    ROTK(0)  ROTK(1)  ROTK(2)  ROTK(3)                                        \
    ROTK(4)  ROTK(5)  ROTK(6)  ROTK(7)                                        \
    ROTK(8)  ROTK(9)  ROTK(10) ROTK(11)                                       \
    ROTK(12) ROTK(13) ROTK(14) ROTK(15)                                       \
    float d1 = d1a + d1b, d2 = d2a + d2b;                                     \
    float p1n = dir ? d1 : d1 * e1, p2n = dir ? d2 : d2 * e2;                 \
    p1 = live ? p1n : p1; p2 = live ? p2n : p2;                               \
  }

#define RESCALE {                                                             \
    float mx = fmaxf(p1, p2);                                                 \
    SWZMAX(mx, 0x041F); SWZMAX(mx, 0x081F);                                   \
    SWZMAX(mx, 0x101F); SWZMAX(mx, 0x201F);                                   \
    int ef = (__float_as_int(mx) >> 23) & 0xFF;                               \
    C2 += ef - 127;                                                           \
    float sc = __int_as_float((254 - ef) << 23);                              \
    p1 *= sc; p2 *= sc; }

  for (; ubase + 8 <= maxIters; ubase += 8) {
    STEP(0, 1) STEP(1, 1) STEP(2, 1) STEP(3, 1)
    STEP(4, 1) STEP(5, 1) STEP(6, 1) STEP(7, 1)
    RESCALE
  }
  {
    int rem = maxIters - ubase;
    if (rem > 0) STEP(0, 0)
    if (rem > 1) STEP(1, 0)
    if (rem > 2) STEP(2, 0)
    if (rem > 3) STEP(3, 0)
    if (rem > 4) STEP(4, 0)
    if (rem > 5) STEP(5, 0)
    if (rem > 6) STEP(6, 0)
  }
  RESCALE   // normalize before the alpha·gamma dot (avoid fp32 overflow)

#undef STEP
#undef ROTK
#undef RESCALE

  // --- epilogue: combine fwd (g even) with bwd partner (g^1) in-wave via LDS ---
  ((float2*)smem)[(rowbase + ws2) >> 1] = make_float2(p1, p2);
  smem[rowbase + 32] = num;
  smem[rowbase + 33] = __int_as_float(C2);
  // same-wave LDS ordering via lgkmcnt (no barrier needed)
  const int pbase = (w * 4 + (g ^ 1)) * RST;
  float2 qq = ((float2*)smem)[(pbase + ws2) >> 1];
  float prod = p1 * qq.x + p2 * qq.y;
  SWZADD(prod, 0x041F); SWZADD(prod, 0x081F);
  SWZADD(prod, 0x101F); SWZADD(prod, 0x201F);
  float onum = smem[pbase + 32];
  int oC2 = __float_as_int(smem[pbase + 33]);
  if (lidx == 0 && dir == 0) {
    float den = LN2F * (lg2(prod) + (float)(C2 + oC2));
    wsr[row] = (num + onum) - den;
    wsl[row] = (float)L;
  }
}

__global__ void crf_reduce(const float* __restrict__ wsr,
                           const float* __restrict__ wsl,
                           float* __restrict__ out)
{
  __shared__ float sr[256], sl[256];
  int t = threadIdx.x;
  float a = 0.0f, c = 0.0f;
  for (int i = t; i < BB; i += 256) { a += wsr[i]; c += wsl[i]; }
  sr[t] = a; sl[t] = c;
  __syncthreads();
  for (int k = 128; k > 0; k >>= 1) {
    if (t < k) { sr[t] += sr[t + k]; sl[t] += sl[t + k]; }
    __syncthreads();
  }
  if (t == 0) out[0] = sr[0] / sl[0];
}

extern "C" void kernel_launch(void* const* d_in, const int* in_sizes, int n_in,
                              void* d_out, int out_size, void* d_ws, size_t ws_size,
                              hipStream_t stream)
{
  const float* em = (const float*)d_in[0];
  const float* st = (const float*)d_in[1];
  const float* en = (const float*)d_in[2];
  const float* tr = (const float*)d_in[3];
  const int*   lb = (const int*)d_in[4];
  const void*  mk = d_in[5];
  float* wsr = (float*)d_ws;
  float* wsl = wsr + BB;
  crf_main<<<BB / 8, 256, 0, stream>>>(em, st, en, tr, lb, mk, wsr, wsl);
  crf_reduce<<<1, 256, 0, stream>>>(wsr, wsl, (float*)d_out);
}

// Round 9
// 122.306 us; speedup vs baseline: 1.1784x; 1.1784x over previous
//
#include <hip/hip_runtime.h>
#include <stdint.h>

#define TT 25
#define SS 512
#define BB 4096
#define RST 36
#define IL2 1.4426950408889634f
#define LN2F 0.6931471805599453f

__device__ __forceinline__ float ex2(float x){ return __builtin_amdgcn_exp2f(x); }
__device__ __forceinline__ float lg2(float x){ return __builtin_amdgcn_logf(x); }

// pin a value into a VGPR: opaque def, LICM can't sink/remat the producer
#define PIN(x) asm volatile("" : "+v"(x))

// row_ror:K within each 16-lane row (VALU pipe, no LDS): dst[i] = src[(i-K)&15]
template<int K>
__device__ __forceinline__ float rotk(float v){
  if constexpr (K == 0) return v;
  else return __int_as_float(__builtin_amdgcn_update_dpp(
      0, __float_as_int(v), 0x120 | K, 0xF, 0xF, true));
}

#define SWZMAX(v,P) v = fmaxf(v, __int_as_float(__builtin_amdgcn_ds_swizzle(__float_as_int(v), P)))
#define SWZADD(v,P) v += __int_as_float(__builtin_amdgcn_ds_swizzle(__float_as_int(v), P))

// mask may arrive as bool(u8), int32, or float32 — detect from first element
__device__ __forceinline__ int mask_at(const void* m, int mode, int idx){
  if (mode == 1) return ((const int*)m)[idx] != 0;
  if (mode == 2) return ((const float*)m)[idx] != 0.0f;
  return ((const unsigned char*)m)[idx] != 0;
}

__global__ __launch_bounds__(256, 2)
void crf_main(const float* __restrict__ em, const float* __restrict__ startp,
              const float* __restrict__ endp, const float* __restrict__ transp,
              const int* __restrict__ labels, const void* __restrict__ maskp,
              float* __restrict__ wsr, float* __restrict__ wsl)
{
  __shared__ float smem[16 * RST];   // epilogue only
  const int tid  = threadIdx.x;
  const int w    = tid >> 6;
  const int lane = tid & 63;
  const int g    = lane >> 4;        // chain-group 0..3 within wave
  const int lidx = lane & 15;
  const int dir  = g & 1;            // 0 = forward, 1 = backward
  const int rsel = g >> 1;           // which of the wave's 2 rows
  const int row  = blockIdx.x * 8 + w * 2 + rsel;
  const int rowbase = (w * 4 + g) * RST;

  const int c1 = 2 * lidx, c2 = 2 * lidx + 1;      // adjacent col pair
  const bool v1 = (c1 < TT), v2 = (c2 < TT);
  const int c1c = v1 ? c1 : (TT - 1), c2c = v2 ? c2 : (TT - 1);
  const int cb  = (lidx < 12) ? c1 : 23;           // pair-load base col (reads cb,cb+1)
  const bool selA = (lidx < 12);                   // emv1 = selA ? x : y
  const int ws2 = (lidx <= 12) ? 2 * lidx : (26 + 2 * (lidx - 13)); // idle dump 26..31

  // --- 32-bit word-offset bases (em < 2^31 words) ---
  const int emW  = row * (SS * TT);                // word idx of row start in em
  const int labW = row * SS;                       // word idx of row start in labels

  // --- mask dtype detection ---
  const uint32_t w0 = ((const uint32_t*)maskp)[0];
  const int mode = (w0 == 1u) ? 1 : ((w0 == 0x3F800000u) ? 2 : 0);

  // --- lengths of the wave's two rows (2-round ballot probes) ---
  int lens[2];
  const int base2row = blockIdx.x * 8 + w * 2;
#pragma unroll
  for (int r = 0; r < 2; ++r) {
    int mb = (base2row + r) * SS;
    int pq1 = mask_at(maskp, mode, mb + lane * 8);
    unsigned long long b1 = __ballot(pq1);
    int q = __popcll(b1);
    int bs = 8 * (q - 1);
    int pq2 = mask_at(maskp, mode, mb + bs + (lane & 7));
    unsigned long long b2 = __ballot((lane < 8) && pq2);
    lens[r] = bs + __popcll(b2);
  }
  const int L = rsel ? lens[1] : lens[0];
  const int m = (L - 1) >> 1;
  const int iters = dir ? (L - 1 - m) : m;
  const int it0 = lens[0] - 1 - ((lens[0] - 1) >> 1);
  const int it1 = lens[1] - 1 - ((lens[1] - 1) >> 1);
  const int maxIters = max(it0, it1);   // bwd count >= fwd count

  // --- pre-rotated weight tables (verified R6-R8). ror:k src lane s=(lidx-k)&15 ---
  float Ea1[16], Eb1[16], Ea2[16], Eb2[16];
#pragma unroll
  for (int k = 0; k < 16; ++k) {
    int s  = (lidx - k) & 15;
    int i1 = 2 * s, i2 = 2 * s + 1;
    bool q1 = (i1 < TT), q2 = (i2 < TT);
    int i1c = q1 ? i1 : 0, i2c = q2 ? i2 : 0;
    float t11 = dir ? transp[c1c * TT + i1c] : transp[i1c * TT + c1c];
    float t21 = dir ? transp[c1c * TT + i2c] : transp[i2c * TT + c1c];
    float t12 = dir ? transp[c2c * TT + i1c] : transp[i1c * TT + c2c];
    float t22 = dir ? transp[c2c * TT + i2c] : transp[i2c * TT + c2c];
    Ea1[k] = (q1 && v1) ? ex2(t11 * IL2) : 0.f;
    Eb1[k] = (q2 && v1) ? ex2(t21 * IL2) : 0.f;
    Ea2[k] = (q1 && v2) ? ex2(t12 * IL2) : 0.f;
    Eb2[k] = (q2 && v2) ? ex2(t22 * IL2) : 0.f;
  }
#pragma unroll
  for (int k = 0; k < 16; ++k) {
    PIN(Ea1[k]); PIN(Eb1[k]); PIN(Ea2[k]); PIN(Eb2[k]);
  }

  // --- init state: fwd alpha0 = exp(start+em0); bwd gamma_{L-1} = exp(end) ---
  float pf1 = startp[c1c] + em[emW + c1c];
  float pf2 = startp[c2c] + em[emW + c2c];
  float p1 = v1 ? ex2((dir ? endp[c1c] : pf1) * IL2) : 0.f;
  float p2 = v2 ? ex2((dir ? endp[c2c] : pf2) * IL2) : 0.f;

  // --- numerator init + label carry ---
  const int l0 = labels[labW];
  const int lE = labels[labW + L - 1];
  float num = dir ? endp[lE] : (startp[l0] + em[emW + l0]);
  int C2 = 0;
  int carry = dir ? lE : l0;

  // --- prefetch rings, depth 4 (raw values; selects/adds at consume) ---
  float emp1[4], emp2[4], tv[4], eg[4];
  int labv[4];
#pragma unroll
  for (int u = 0; u < 4; ++u) {
    int t  = dir ? (L - 1 - u) : (1 + u);       // safe: L>=256
    int o  = emW + t * TT + cb;
    emp1[u] = em[o];
    emp2[u] = em[o + 1];
    int ni = dir ? (L - 2 - u) : (1 + u);
    int nl = labels[labW + ni];
    int aL = dir ? nl : carry, bL = dir ? carry : nl;
    tv[u] = transp[aL * TT + bL];
    eg[u] = em[emW + t * TT + bL];
    carry = nl;
    labv[u] = labels[labW + (dir ? (L - 6 - u) : (5 + u))];  // labels 5..8 ahead
  }

  // running fill offsets: next fill targets step vf=4
  int emOff  = emW + (dir ? (L - 5) * TT : 5 * TT) + cb;
  int labOff = labW + (dir ? (L - 10) : 9);
  const int dstep = dir ? -TT : TT;
  const int dlab  = dir ? -1 : 1;

  int ubase = 0;

#define ROTK(K)                                                               \
    { float r1 = rotk<K>(w1), r2 = rotk<K>(w2v);                              \
      d1a = fmaf(r1, Ea1[K], d1a); d1b = fmaf(r2, Eb1[K], d1b);               \
      d2a = fmaf(r1, Ea2[K], d2a); d2b = fmaf(r2, Eb2[K], d2b); }

#define STEP(u, FILL)                                                         \
  {                                                                           \
    bool live = (ubase + (u)) < iters;                                        \
    float ev1 = selA ? emp1[u] : emp2[u];                                     \
    float ev2 = emp2[u];                                                      \
    float e1 = ex2(ev1 * IL2), e2 = ex2(ev2 * IL2);                           \
    float ta = tv[u] + eg[u];                                                 \
    num += live ? ta : 0.f;                                                   \
    if (FILL) {                                                               \
      emp1[u] = em[emOff];                                                    \
      emp2[u] = em[emOff + 1];                                                \
      int nl = labv[u];                                                       \
      int aL = dir ? nl : carry, bL = dir ? carry : nl;                       \
      tv[u] = transp[aL * TT + bL];                                           \
      int ego = max(emOff + bL - cb, emW);                                    \
      eg[u] = em[ego];                                                        \
      labv[u] = labels[labOff];                                               \
      carry = nl;                                                             \
      emOff  = max(emOff + dstep, emW);                                       \
      labOff = max(labOff + dlab, labW);                                      \
    }                                                                         \
    float w1 = dir ? p1 * e1 : p1, w2v = dir ? p2 * e2 : p2;                  \
    float d1a = 0.f, d1b = 0.f, d2a = 0.f, d2b = 0.f;                         \
    ROTK(0)  ROTK(1)  ROTK(2)  ROTK(3)                                        \
    ROTK(4)  ROTK(5)  ROTK(6)  ROTK(7)                                        \
    ROTK(8)  ROTK(9)  ROTK(10) ROTK(11)                                       \
    ROTK(12) ROTK(13) ROTK(14) ROTK(15)                                       \
    float d1 = d1a + d1b, d2 = d2a + d2b;                                     \
    float p1n = dir ? d1 : d1 * e1, p2n = dir ? d2 : d2 * e2;                 \
    p1 = live ? p1n : p1; p2 = live ? p2n : p2;                               \
  }

#define RESCALE {                                                             \
    float mx = fmaxf(p1, p2);                                                 \
    SWZMAX(mx, 0x041F); SWZMAX(mx, 0x081F);                                   \
    SWZMAX(mx, 0x101F); SWZMAX(mx, 0x201F);                                   \
    int ef = (__float_as_int(mx) >> 23) & 0xFF;                               \
    C2 += ef - 127;                                                           \
    float sc = __int_as_float((254 - ef) << 23);                              \
    p1 *= sc; p2 *= sc; }

  for (; ubase + 8 <= maxIters; ubase += 8) {
    STEP(0, 1) STEP(1, 1) STEP(2, 1) STEP(3, 1)
    STEP(0, 1) STEP(1, 1) STEP(2, 1) STEP(3, 1)
    RESCALE
  }
  {
    int rem = maxIters - ubase;   // 0..7; fills stay clamped-safe
    if (rem > 0) STEP(0, 1)
    if (rem > 1) STEP(1, 1)
    if (rem > 2) STEP(2, 1)
    if (rem > 3) STEP(3, 1)
    if (rem > 4) STEP(0, 0)
    if (rem > 5) STEP(1, 0)
    if (rem > 6) STEP(2, 0)
  }
  RESCALE   // normalize before the alpha·gamma dot (avoid fp32 overflow)

#undef STEP
#undef ROTK
#undef RESCALE

  // --- epilogue: combine fwd (g even) with bwd partner (g^1) in-wave via LDS ---
  ((float2*)smem)[(rowbase + ws2) >> 1] = make_float2(p1, p2);
  smem[rowbase + 32] = num;
  smem[rowbase + 33] = __int_as_float(C2);
  // same-wave LDS ordering via lgkmcnt (no barrier needed)
  const int pbase = (w * 4 + (g ^ 1)) * RST;
  float2 qq = ((float2*)smem)[(pbase + ws2) >> 1];
  float prod = p1 * qq.x + p2 * qq.y;
  SWZADD(prod, 0x041F); SWZADD(prod, 0x081F);
  SWZADD(prod, 0x101F); SWZADD(prod, 0x201F);
  float onum = smem[pbase + 32];
  int oC2 = __float_as_int(smem[pbase + 33]);
  if (lidx == 0 && dir == 0) {
    float den = LN2F * (lg2(prod) + (float)(C2 + oC2));
    wsr[row] = (num + onum) - den;
    wsl[row] = (float)L;
  }
}

__global__ void crf_reduce(const float* __restrict__ wsr,
                           const float* __restrict__ wsl,
                           float* __restrict__ out)
{
  __shared__ float sr[256], sl[256];
  int t = threadIdx.x;
  float a = 0.0f, c = 0.0f;
  for (int i = t; i < BB; i += 256) { a += wsr[i]; c += wsl[i]; }
  sr[t] = a; sl[t] = c;
  __syncthreads();
  for (int k = 128; k > 0; k >>= 1) {
    if (t < k) { sr[t] += sr[t + k]; sl[t] += sl[t + k]; }
    __syncthreads();
  }
  if (t == 0) out[0] = sr[0] / sl[0];
}

extern "C" void kernel_launch(void* const* d_in, const int* in_sizes, int n_in,
                              void* d_out, int out_size, void* d_ws, size_t ws_size,
                              hipStream_t stream)
{
  const float* em = (const float*)d_in[0];
  const float* st = (const float*)d_in[1];
  const float* en = (const float*)d_in[2];
  const float* tr = (const float*)d_in[3];
  const int*   lb = (const int*)d_in[4];
  const void*  mk = d_in[5];
  float* wsr = (float*)d_ws;
  float* wsl = wsr + BB;
  crf_main<<<BB / 8, 256, 0, stream>>>(em, st, en, tr, lb, mk, wsr, wsl);
  crf_reduce<<<1, 256, 0, stream>>>(wsr, wsl, (float*)d_out);
}